// Round 17
// baseline (205.588 us; speedup 1.0000x reference)
//
#include <hip/hip_runtime.h>
#include <hip/hip_fp8.h>
#include <stdint.h>

#define N_CLS 8192
#define FEAT  512                           // elements; fp8 -> 512 B per row
#define BATCH 1024
#define NTI   32                            // 256-row tiles
#define NTJ   64                            // 128-col tiles
#define NPAIR 1056                          // #{(i,j): j in [2i, 64)} = 8*132
#define NSLOT 8                             // FEAT/64 (K=64 per slot)
#define SLOTB 24576                         // bytes/slot: A 256*64 + B 128*64

typedef __attribute__((ext_vector_type(4))) float f32x4;
typedef __attribute__((ext_vector_type(2))) long longx2;

__device__ inline unsigned char f2fp8(float x) {
    __hip_fp8_e4m3 q(x);                    // OCP e4m3 (gfx950), HW convert
    return q.__x;
}

// ---------------- Kernel 1: sequential EMA per label -> fp8 protos ---------
// float4 loads (lane owns 8 contiguous floats = 32 B), packed 8-B fp8
// stores. Per-class updates applied in batch order (ballot + ctz).
__global__ __launch_bounds__(256) void ema_kernel(
    const float* __restrict__ features, const int* __restrict__ labels,
    const float* __restrict__ protos,
    unsigned char* __restrict__ Phi8, float* __restrict__ rowsum) {
    const int row  = blockIdx.x * 4 + (threadIdx.x >> 6);
    const int lane = threadIdx.x & 63;
    if (lane == 0) rowsum[row] = 0.f;

    f32x4 p0 = *(const f32x4*)&protos[(size_t)row * FEAT + lane * 8];
    f32x4 p1 = *(const f32x4*)&protos[(size_t)row * FEAT + lane * 8 + 4];

    for (int c = 0; c < BATCH / 64; ++c) {
        int lab = labels[c * 64 + lane];
        unsigned long long m = __ballot(lab == row);
        while (m) {
            int b = __builtin_ctzll(m);     // earliest remaining sample
            m &= m - 1;
            int s = c * 64 + b;
            f32x4 f0 = *(const f32x4*)&features[(size_t)s * FEAT + lane * 8];
            f32x4 f1 = *(const f32x4*)&features[(size_t)s * FEAT + lane * 8 + 4];
            p0 = p0 * 0.95f + f0 * 0.05f;
            p1 = p1 * 0.95f + f1 * 0.05f;
            float ss = p0[0]*p0[0] + p0[1]*p0[1] + p0[2]*p0[2] + p0[3]*p0[3]
                     + p1[0]*p1[0] + p1[1]*p1[1] + p1[2]*p1[2] + p1[3]*p1[3];
            #pragma unroll
            for (int off = 32; off; off >>= 1) ss += __shfl_xor(ss, off);
            float inv = 1.0f / fmaxf(sqrtf(ss), 1e-12f);
            p0 *= inv; p1 *= inv;
        }
    }
    unsigned long long packed = 0;
    #pragma unroll
    for (int jj = 0; jj < 4; ++jj)
        packed |= (unsigned long long)f2fp8(p0[jj]) << (8 * jj);
    #pragma unroll
    for (int jj = 0; jj < 4; ++jj)
        packed |= (unsigned long long)f2fp8(p1[jj]) << (8 * (jj + 4));
    *(unsigned long long*)&Phi8[(size_t)row * FEAT + lane * 8] = packed;
}

// ---------------- Kernel 2: 256x128 rect Gram tiles + fused loss -----------
// VERBATIM R10/R14 inner structure (42.4 us, 0 bank conflicts, VGPR 64,
// no spill): ring-3 K=64 slots, vmcnt(3) counted waits, 1 barrier/slot,
// XOR-swizzled LDS, fp8-pair MFMAs. Last finishing block (done-counter)
// reduces rowsum -> loss (R15-proven device-scope machinery).
__global__ __launch_bounds__(512, 4) void gemm_disp_kernel(
    const unsigned char* __restrict__ Phi8, float* __restrict__ rowsum,
    int* __restrict__ done, float* __restrict__ out) {
    __shared__ __align__(16) char smem[3 * SLOTB];   // 72 KiB

    // XCD-aware swizzle (1056 = 8*132)
    int bid = blockIdx.x;
    int u = (bid & 7) * (NPAIR / 8) + (bid >> 3);
    int i = 0;
    while (u >= NTJ - 2 * i) { u -= NTJ - 2 * i; ++i; }
    const int j = 2 * i + u;                // j >= 2i
    const bool diagovl = ((j >> 1) == i);   // col-range overlaps row-range

    const int w    = threadIdx.x >> 6;      // wave 0..7
    const int lane = threadIdx.x & 63;
    const int wr = w >> 1, wc = w & 1;      // 4x2 waves, 64x64 each
    const int h = lane >> 4;                // k-group 0..3
    const int r = lane & 15;                // fragment row/col
    const int rseg = (h ^ ((r >> 1) & 3)) * 16;  // swizzled 16B segment

    const int Ibase = i * 256, Jbase = j * 128;

    f32x4 acc[4][4];
    #pragma unroll
    for (int m = 0; m < 4; ++m)
        #pragma unroll
        for (int n = 0; n < 4; ++n) acc[m][n] = (f32x4){0.f, 0.f, 0.f, 0.f};

    // staging: per slot 24 KB = 24 wave-loads -> uniform 3/wave:
    // A (16 KB): 2 loads, rows w*32+c*16+(lane>>2); B (8 KB): 1 load,
    // rows w*16+(lane>>2). 4 lanes/row, 16B blocks, source pre-swizzled.
    const int srow = lane >> 2;             // 0..15
    const int sseg = (lane & 3) ^ ((lane >> 3) & 3);
    const unsigned char* gA =
        Phi8 + (size_t)(Ibase + w * 32 + srow) * FEAT + sseg * 16;
    const unsigned char* gB =
        Phi8 + (size_t)(Jbase + w * 16 + srow) * FEAT + sseg * 16;

#define STAGE(s)                                                              \
    {                                                                         \
        char* base = smem + ((s) % 3) * SLOTB;                                \
        __builtin_amdgcn_global_load_lds(                                     \
            (const __attribute__((address_space(1))) void*)(gA + (s) * 64),   \
            (__attribute__((address_space(3))) void*)(base + w * 2048),       \
            16, 0, 0);                                                        \
        __builtin_amdgcn_global_load_lds(                                     \
            (const __attribute__((address_space(1))) void*)(gA + 16 * FEAT + (s) * 64), \
            (__attribute__((address_space(3))) void*)(base + w * 2048 + 1024),\
            16, 0, 0);                                                        \
        __builtin_amdgcn_global_load_lds(                                     \
            (const __attribute__((address_space(1))) void*)(gB + (s) * 64),   \
            (__attribute__((address_space(3))) void*)(base + 16384 + w * 1024),\
            16, 0, 0);                                                        \
    }

#define MF8(ai, bi, mi, ni)                                                   \
    acc[mi][ni] = __builtin_amdgcn_mfma_f32_16x16x32_fp8_fp8(                 \
        ai[0], bi[0], acc[mi][ni], 0, 0, 0);                                  \
    acc[mi][ni] = __builtin_amdgcn_mfma_f32_16x16x32_fp8_fp8(                 \
        ai[1], bi[1], acc[mi][ni], 0, 0, 0);

#define SLOT(s, TAIL)                                                         \
    {                                                                         \
        const char* As = smem + ((s) % 3) * SLOTB;                            \
        const char* Bs = As + 16384;                                          \
        longx2 a0, a1, a2, a3, b0, b1, b2, b3;                                \
        b0 = *(const longx2*)(Bs + (wc * 64 +  0 + r) * 64 + rseg);           \
        b1 = *(const longx2*)(Bs + (wc * 64 + 16 + r) * 64 + rseg);           \
        b2 = *(const longx2*)(Bs + (wc * 64 + 32 + r) * 64 + rseg);           \
        b3 = *(const longx2*)(Bs + (wc * 64 + 48 + r) * 64 + rseg);           \
        a0 = *(const longx2*)(As + (wr * 64 +  0 + r) * 64 + rseg);           \
        a1 = *(const longx2*)(As + (wr * 64 + 16 + r) * 64 + rseg);           \
        a2 = *(const longx2*)(As + (wr * 64 + 32 + r) * 64 + rseg);           \
        a3 = *(const longx2*)(As + (wr * 64 + 48 + r) * 64 + rseg);           \
        __builtin_amdgcn_s_setprio(1);                                        \
        MF8(a0, b0, 0, 0) MF8(a1, b0, 1, 0) MF8(a2, b0, 2, 0) MF8(a3, b0, 3, 0) \
        MF8(a0, b1, 0, 1) MF8(a1, b1, 1, 1) MF8(a2, b1, 2, 1) MF8(a3, b1, 3, 1) \
        MF8(a0, b2, 0, 2) MF8(a1, b2, 1, 2) MF8(a2, b2, 2, 2) MF8(a3, b2, 3, 2) \
        MF8(a0, b3, 0, 3) MF8(a1, b3, 1, 3) MF8(a2, b3, 2, 3) MF8(a3, b3, 3, 3) \
        __builtin_amdgcn_s_setprio(0);                                        \
        TAIL                                                                  \
    }

#define TAIL_MID(s)                                                           \
    STAGE((s) + 2)                                                            \
    asm volatile("s_waitcnt vmcnt(3)" ::: "memory");                          \
    __builtin_amdgcn_s_barrier();
#define TAIL_6                                                                \
    asm volatile("s_waitcnt vmcnt(0)" ::: "memory");                          \
    __builtin_amdgcn_s_barrier();
#define TAIL_7

    // prologue: stage slots 0,1; wait slot 0 landed (slot 1 stays in flight)
    STAGE(0) STAGE(1)
    asm volatile("s_waitcnt vmcnt(3)" ::: "memory");
    __builtin_amdgcn_s_barrier();

    SLOT(0, TAIL_MID(0)) SLOT(1, TAIL_MID(1)) SLOT(2, TAIL_MID(2))
    SLOT(3, TAIL_MID(3)) SLOT(4, TAIL_MID(4)) SLOT(5, TAIL_MID(5))
    SLOT(6, TAIL_6)
    SLOT(7, TAIL_7)

    // epilogue: e = exp(10*S); zero exact diagonal on overlap blocks
    // D layout: row = 4*h + q, col = r (HW-verified, dtype-independent)
    #pragma unroll
    for (int m = 0; m < 4; ++m)
        #pragma unroll
        for (int n = 0; n < 4; ++n)
            #pragma unroll
            for (int q = 0; q < 4; ++q) {
                float v = __expf(acc[m][n][q] * 10.0f);
                if (diagovl &&
                    (Ibase + wr * 64 + m * 16 + h * 4 + q) ==
                    (Jbase + wc * 64 + n * 16 + r))
                    v = 0.f;
                acc[m][n][q] = v;
            }

    // row credit (always): rowsum[Ibase + wr*64 + m*16 + 4h+q]
    #pragma unroll
    for (int m = 0; m < 4; ++m) {
        float rs[4];
        #pragma unroll
        for (int q = 0; q < 4; ++q)
            rs[q] = acc[m][0][q] + acc[m][1][q] + acc[m][2][q] + acc[m][3][q];
        #pragma unroll
        for (int q = 0; q < 4; ++q)
            #pragma unroll
            for (int off = 1; off < 16; off <<= 1) rs[q] += __shfl_xor(rs[q], off);
        if (r == 0) {
            #pragma unroll
            for (int q = 0; q < 4; ++q)
                atomicAdd(&rowsum[Ibase + wr * 64 + m * 16 + h * 4 + q], rs[q]);
        }
    }

    // col credit (only when mirror entry is NOT computed elsewhere): j >= 2i+2
    if (!diagovl) {
        #pragma unroll
        for (int n = 0; n < 4; ++n) {
            float cs = 0.f;
            #pragma unroll
            for (int m = 0; m < 4; ++m)
                #pragma unroll
                for (int q = 0; q < 4; ++q) cs += acc[m][n][q];
            cs += __shfl_xor(cs, 16);
            cs += __shfl_xor(cs, 32);
            if (lane < 16)
                atomicAdd(&rowsum[Jbase + wc * 64 + n * 16 + r], cs);
        }
    }

    // fused loss: the LAST of the 1056 blocks reduces rowsum -> out.
    // Device-scope: __threadfence publishes this block's atomics before the
    // counter bump; the last block reads rowsum via atomicAdd(p, 0.f)
    // (device-scope RMW; machinery hardware-verified in R15).
    __threadfence();
    __shared__ int islast;
    __shared__ float red[8];
    if (threadIdx.x == 0) islast = (atomicAdd(done, 1) == NPAIR - 1) ? 1 : 0;
    __syncthreads();
    if (islast) {
        float s = 0.f;
        for (int idx = (int)threadIdx.x; idx < N_CLS; idx += 512) {
            float v = atomicAdd(&rowsum[idx], 0.0f);
            s += logf(v * (1.0f / (float)(N_CLS - 1)));
        }
        #pragma unroll
        for (int off = 32; off; off >>= 1) s += __shfl_xor(s, off);
        if (lane == 0) red[w] = s;
        __syncthreads();
        if (threadIdx.x == 0) {
            float tot = 0.f;
            #pragma unroll
            for (int t = 0; t < 8; ++t) tot += red[t];
            out[0] = tot * (1.0f / (float)N_CLS);
        }
    }
}

extern "C" void kernel_launch(void* const* d_in, const int* in_sizes, int n_in,
                              void* d_out, int out_size, void* d_ws, size_t ws_size,
                              hipStream_t stream) {
    (void)in_sizes; (void)n_in; (void)out_size; (void)ws_size;
    const float* features = (const float*)d_in[0];
    const int*   labels   = (const int*)d_in[1];
    const float* protos   = (const float*)d_in[2];
    float* out = (float*)d_out;

    unsigned char* Phi8 = (unsigned char*)d_ws;                     // 4 MiB
    float* rowsum = (float*)(Phi8 + (size_t)N_CLS * FEAT);          // 32 KiB
    int* done = (int*)(rowsum + N_CLS);

    hipMemsetAsync(done, 0, sizeof(int), stream);
    ema_kernel<<<N_CLS / 4, 256, 0, stream>>>(features, labels, protos, Phi8, rowsum);
    gemm_disp_kernel<<<NPAIR, 512, 0, stream>>>(Phi8, rowsum, done, out);
}

// Round 18
// 58.753 us; speedup vs baseline: 3.4992x; 3.4992x over previous
//
#include <hip/hip_runtime.h>
#include <hip/hip_fp8.h>
#include <stdint.h>

#define N_CLS 8192
#define FEAT  512                           // elements; fp8 -> 512 B per row
#define BATCH 1024
#define NTI   32                            // 256-row tiles
#define NTJ   64                            // 128-col tiles
#define NPAIR 1056                          // #{(i,j): j in [2i, 64)} = 8*132
#define NSLOT 8                             // FEAT/64 (K=64 per slot)
#define SLOTB 24576                         // bytes/slot: A 256*64 + B 128*64

typedef __attribute__((ext_vector_type(4))) float f32x4;
typedef __attribute__((ext_vector_type(2))) long longx2;

__device__ inline unsigned char f2fp8(float x) {
    __hip_fp8_e4m3 q(x);                    // OCP e4m3 (gfx950), HW convert
    return q.__x;
}

// ---------------- Kernel 1: sequential EMA per label -> fp8 protos ---------
// float4 loads, packed 8-B fp8 stores; 1-deep prefetch of the next matched
// sample's feature vector (refcheck'd in R15) hides the serial chain.
__global__ __launch_bounds__(256) void ema_kernel(
    const float* __restrict__ features, const int* __restrict__ labels,
    const float* __restrict__ protos,
    unsigned char* __restrict__ Phi8, float* __restrict__ rowsum) {
    const int row  = blockIdx.x * 4 + (threadIdx.x >> 6);
    const int lane = threadIdx.x & 63;
    if (lane == 0) rowsum[row] = 0.f;

    f32x4 p0 = *(const f32x4*)&protos[(size_t)row * FEAT + lane * 8];
    f32x4 p1 = *(const f32x4*)&protos[(size_t)row * FEAT + lane * 8 + 4];

    for (int c = 0; c < BATCH / 64; ++c) {
        int lab = labels[c * 64 + lane];
        unsigned long long m = __ballot(lab == row);
        if (!m) continue;
        int s = c * 64 + __builtin_ctzll(m);
        f32x4 f0 = *(const f32x4*)&features[(size_t)s * FEAT + lane * 8];
        f32x4 f1 = *(const f32x4*)&features[(size_t)s * FEAT + lane * 8 + 4];
        while (true) {
            m &= m - 1;
            f32x4 cf0 = f0, cf1 = f1;
            if (m) {                        // prefetch next match
                int s2 = c * 64 + __builtin_ctzll(m);
                f0 = *(const f32x4*)&features[(size_t)s2 * FEAT + lane * 8];
                f1 = *(const f32x4*)&features[(size_t)s2 * FEAT + lane * 8 + 4];
            }
            p0 = p0 * 0.95f + cf0 * 0.05f;
            p1 = p1 * 0.95f + cf1 * 0.05f;
            float ss = p0[0]*p0[0] + p0[1]*p0[1] + p0[2]*p0[2] + p0[3]*p0[3]
                     + p1[0]*p1[0] + p1[1]*p1[1] + p1[2]*p1[2] + p1[3]*p1[3];
            #pragma unroll
            for (int off = 32; off; off >>= 1) ss += __shfl_xor(ss, off);
            float inv = 1.0f / fmaxf(sqrtf(ss), 1e-12f);
            p0 *= inv; p1 *= inv;
            if (!m) break;
        }
    }
    unsigned long long packed = 0;
    #pragma unroll
    for (int jj = 0; jj < 4; ++jj)
        packed |= (unsigned long long)f2fp8(p0[jj]) << (8 * jj);
    #pragma unroll
    for (int jj = 0; jj < 4; ++jj)
        packed |= (unsigned long long)f2fp8(p1[jj]) << (8 * (jj + 4));
    *(unsigned long long*)&Phi8[(size_t)row * FEAT + lane * 8] = packed;
}

// ---------------- Kernel 2: 256x128 rect Gram tiles, fp8-pair, ring-3 ------
// VERBATIM R10/R14 (measured 42.4 us, 0 bank conflicts, VGPR 64, no spill).
// K=64 slots; 64-B rows, XOR'd 16-B segments, ds_read_b128; low/high 8 B
// feed paired fp8 MFMAs (same k-map for A and B => Gram-correct).
// Ring of 3 slots, staged 2 ahead, uniform 3 loads/wave/slot, vmcnt(3).
__global__ __launch_bounds__(512, 4) void gemm_disp_kernel(
    const unsigned char* __restrict__ Phi8, float* __restrict__ rowsum) {
    __shared__ __align__(16) char smem[3 * SLOTB];   // 72 KiB

    // XCD-aware swizzle (1056 = 8*132)
    int bid = blockIdx.x;
    int u = (bid & 7) * (NPAIR / 8) + (bid >> 3);
    int i = 0;
    while (u >= NTJ - 2 * i) { u -= NTJ - 2 * i; ++i; }
    const int j = 2 * i + u;                // j >= 2i
    const bool diagovl = ((j >> 1) == i);   // col-range overlaps row-range

    const int w    = threadIdx.x >> 6;      // wave 0..7
    const int lane = threadIdx.x & 63;
    const int wr = w >> 1, wc = w & 1;      // 4x2 waves, 64x64 each
    const int h = lane >> 4;                // k-group 0..3
    const int r = lane & 15;                // fragment row/col
    const int rseg = (h ^ ((r >> 1) & 3)) * 16;  // swizzled 16B segment

    const int Ibase = i * 256, Jbase = j * 128;

    f32x4 acc[4][4];
    #pragma unroll
    for (int m = 0; m < 4; ++m)
        #pragma unroll
        for (int n = 0; n < 4; ++n) acc[m][n] = (f32x4){0.f, 0.f, 0.f, 0.f};

    // staging: per slot 24 KB = 24 wave-loads -> uniform 3/wave:
    // A (16 KB): 2 loads, rows w*32+c*16+(lane>>2); B (8 KB): 1 load,
    // rows w*16+(lane>>2). 4 lanes/row, 16B blocks, source pre-swizzled.
    const int srow = lane >> 2;             // 0..15
    const int sseg = (lane & 3) ^ ((lane >> 3) & 3);
    const unsigned char* gA =
        Phi8 + (size_t)(Ibase + w * 32 + srow) * FEAT + sseg * 16;
    const unsigned char* gB =
        Phi8 + (size_t)(Jbase + w * 16 + srow) * FEAT + sseg * 16;

#define STAGE(s)                                                              \
    {                                                                         \
        char* base = smem + ((s) % 3) * SLOTB;                                \
        __builtin_amdgcn_global_load_lds(                                     \
            (const __attribute__((address_space(1))) void*)(gA + (s) * 64),   \
            (__attribute__((address_space(3))) void*)(base + w * 2048),       \
            16, 0, 0);                                                        \
        __builtin_amdgcn_global_load_lds(                                     \
            (const __attribute__((address_space(1))) void*)(gA + 16 * FEAT + (s) * 64), \
            (__attribute__((address_space(3))) void*)(base + w * 2048 + 1024),\
            16, 0, 0);                                                        \
        __builtin_amdgcn_global_load_lds(                                     \
            (const __attribute__((address_space(1))) void*)(gB + (s) * 64),   \
            (__attribute__((address_space(3))) void*)(base + 16384 + w * 1024),\
            16, 0, 0);                                                        \
    }

#define MF8(ai, bi, mi, ni)                                                   \
    acc[mi][ni] = __builtin_amdgcn_mfma_f32_16x16x32_fp8_fp8(                 \
        ai[0], bi[0], acc[mi][ni], 0, 0, 0);                                  \
    acc[mi][ni] = __builtin_amdgcn_mfma_f32_16x16x32_fp8_fp8(                 \
        ai[1], bi[1], acc[mi][ni], 0, 0, 0);

#define SLOT(s, TAIL)                                                         \
    {                                                                         \
        const char* As = smem + ((s) % 3) * SLOTB;                            \
        const char* Bs = As + 16384;                                          \
        longx2 a0, a1, a2, a3, b0, b1, b2, b3;                                \
        b0 = *(const longx2*)(Bs + (wc * 64 +  0 + r) * 64 + rseg);           \
        b1 = *(const longx2*)(Bs + (wc * 64 + 16 + r) * 64 + rseg);           \
        b2 = *(const longx2*)(Bs + (wc * 64 + 32 + r) * 64 + rseg);           \
        b3 = *(const longx2*)(Bs + (wc * 64 + 48 + r) * 64 + rseg);           \
        a0 = *(const longx2*)(As + (wr * 64 +  0 + r) * 64 + rseg);           \
        a1 = *(const longx2*)(As + (wr * 64 + 16 + r) * 64 + rseg);           \
        a2 = *(const longx2*)(As + (wr * 64 + 32 + r) * 64 + rseg);           \
        a3 = *(const longx2*)(As + (wr * 64 + 48 + r) * 64 + rseg);           \
        __builtin_amdgcn_s_setprio(1);                                        \
        MF8(a0, b0, 0, 0) MF8(a1, b0, 1, 0) MF8(a2, b0, 2, 0) MF8(a3, b0, 3, 0) \
        MF8(a0, b1, 0, 1) MF8(a1, b1, 1, 1) MF8(a2, b1, 2, 1) MF8(a3, b1, 3, 1) \
        MF8(a0, b2, 0, 2) MF8(a1, b2, 1, 2) MF8(a2, b2, 2, 2) MF8(a3, b2, 3, 2) \
        MF8(a0, b3, 0, 3) MF8(a1, b3, 1, 3) MF8(a2, b3, 2, 3) MF8(a3, b3, 3, 3) \
        __builtin_amdgcn_s_setprio(0);                                        \
        TAIL                                                                  \
    }

#define TAIL_MID(s)                                                           \
    STAGE((s) + 2)                                                            \
    asm volatile("s_waitcnt vmcnt(3)" ::: "memory");                          \
    __builtin_amdgcn_s_barrier();
#define TAIL_6                                                                \
    asm volatile("s_waitcnt vmcnt(0)" ::: "memory");                          \
    __builtin_amdgcn_s_barrier();
#define TAIL_7

    // prologue: stage slots 0,1; wait slot 0 landed (slot 1 stays in flight)
    STAGE(0) STAGE(1)
    asm volatile("s_waitcnt vmcnt(3)" ::: "memory");
    __builtin_amdgcn_s_barrier();

    SLOT(0, TAIL_MID(0)) SLOT(1, TAIL_MID(1)) SLOT(2, TAIL_MID(2))
    SLOT(3, TAIL_MID(3)) SLOT(4, TAIL_MID(4)) SLOT(5, TAIL_MID(5))
    SLOT(6, TAIL_6)
    SLOT(7, TAIL_7)

    // epilogue: e = exp(10*S); zero exact diagonal on overlap blocks
    // D layout: row = 4*h + q, col = r (HW-verified, dtype-independent)
    #pragma unroll
    for (int m = 0; m < 4; ++m)
        #pragma unroll
        for (int n = 0; n < 4; ++n)
            #pragma unroll
            for (int q = 0; q < 4; ++q) {
                float v = __expf(acc[m][n][q] * 10.0f);
                if (diagovl &&
                    (Ibase + wr * 64 + m * 16 + h * 4 + q) ==
                    (Jbase + wc * 64 + n * 16 + r))
                    v = 0.f;
                acc[m][n][q] = v;
            }

    // row credit (always): rowsum[Ibase + wr*64 + m*16 + 4h+q]
    #pragma unroll
    for (int m = 0; m < 4; ++m) {
        float rs[4];
        #pragma unroll
        for (int q = 0; q < 4; ++q)
            rs[q] = acc[m][0][q] + acc[m][1][q] + acc[m][2][q] + acc[m][3][q];
        #pragma unroll
        for (int q = 0; q < 4; ++q)
            #pragma unroll
            for (int off = 1; off < 16; off <<= 1) rs[q] += __shfl_xor(rs[q], off);
        if (r == 0) {
            #pragma unroll
            for (int q = 0; q < 4; ++q)
                atomicAdd(&rowsum[Ibase + wr * 64 + m * 16 + h * 4 + q], rs[q]);
        }
    }

    // col credit (only when mirror entry is NOT computed elsewhere): j >= 2i+2
    if (!diagovl) {
        #pragma unroll
        for (int n = 0; n < 4; ++n) {
            float cs = 0.f;
            #pragma unroll
            for (int m = 0; m < 4; ++m)
                #pragma unroll
                for (int q = 0; q < 4; ++q) cs += acc[m][n][q];
            cs += __shfl_xor(cs, 16);
            cs += __shfl_xor(cs, 32);
            if (lane < 16)
                atomicAdd(&rowsum[Jbase + wc * 64 + n * 16 + r], cs);
        }
    }
}

// ---------------- Kernel 3: loss = mean(log(rowsum / (n-1))) ---------------
__global__ __launch_bounds__(512) void loss_kernel(
    const float* __restrict__ rowsum, float* __restrict__ out) {
    __shared__ float red[8];
    float s = 0.f;
    for (int i = threadIdx.x; i < N_CLS; i += 512)
        s += logf(rowsum[i] * (1.0f / (float)(N_CLS - 1)));
    #pragma unroll
    for (int off = 32; off; off >>= 1) s += __shfl_xor(s, off);
    if ((threadIdx.x & 63) == 0) red[threadIdx.x >> 6] = s;
    __syncthreads();
    if (threadIdx.x == 0) {
        float tot = 0.f;
        #pragma unroll
        for (int i = 0; i < 8; ++i) tot += red[i];
        out[0] = tot * (1.0f / (float)N_CLS);
    }
}

extern "C" void kernel_launch(void* const* d_in, const int* in_sizes, int n_in,
                              void* d_out, int out_size, void* d_ws, size_t ws_size,
                              hipStream_t stream) {
    (void)in_sizes; (void)n_in; (void)out_size; (void)ws_size;
    const float* features = (const float*)d_in[0];
    const int*   labels   = (const int*)d_in[1];
    const float* protos   = (const float*)d_in[2];
    float* out = (float*)d_out;

    unsigned char* Phi8 = (unsigned char*)d_ws;                     // 4 MiB
    float* rowsum = (float*)(Phi8 + (size_t)N_CLS * FEAT);          // 32 KiB

    ema_kernel<<<N_CLS / 4, 256, 0, stream>>>(features, labels, protos, Phi8, rowsum);
    gemm_disp_kernel<<<NPAIR, 512, 0, stream>>>(Phi8, rowsum);
    loss_kernel<<<1, 512, 0, stream>>>(rowsum, out);
}